// Round 1
// baseline (159.089 us; speedup 1.0000x reference)
//
#include <hip/hip_runtime.h>
#include <stdint.h>

// GPT2 attention fused pipeline, MI355X/gfx950.
// B=2, S=2048, H=768, nh=12, hd=64. fp32 I/O, bf16 internal compute (MFMA).

#define B_   2
#define S_   2048
#define H_   768
#define NH_  12
#define HD_  64
#define M_   4096      // B_*S_
#define K_   768
#define N_QKV 2304
#define QKV_ELEMS (B_*NH_*S_*HD_)   // 3145728 per tensor (Q or K or V)

using bf16x8 = __attribute__((ext_vector_type(8))) __bf16;
using f32x4  = __attribute__((ext_vector_type(4))) float;

__device__ inline unsigned short f2bf(float f) {
  unsigned int u = __float_as_uint(f);
  u = (u + 0x7FFFu + ((u >> 16) & 1u)) >> 16;   // RNE
  return (unsigned short)u;
}

// ---------------- cast fp32 -> bf16 (3 tensors in one launch) ----------------
__global__ void cast3(const float* __restrict__ s0, unsigned short* __restrict__ d0, int n0f,
                      const float* __restrict__ s1, unsigned short* __restrict__ d1, int n1f,
                      const float* __restrict__ s2, unsigned short* __restrict__ d2, int n2f) {
  int i = blockIdx.x * blockDim.x + threadIdx.x;
  const float* s; unsigned short* d; int j;
  if (i < n0f)                { s = s0; d = d0; j = i; }
  else if (i < n0f + n1f)     { s = s1; d = d1; j = i - n0f; }
  else if (i < n0f + n1f + n2f) { s = s2; d = d2; j = i - n0f - n1f; }
  else return;
  float4 v = reinterpret_cast<const float4*>(s)[j];
  ushort4 o;
  o.x = f2bf(v.x); o.y = f2bf(v.y); o.z = f2bf(v.z); o.w = f2bf(v.w);
  reinterpret_cast<ushort4*>(d)[j] = o;
}

// ---------------- NT GEMM: C[m,n] = sum_k A[m,k]*Bw[n,k] + bias[n] ----------------
// A: (M_,768) bf16 row-major, Bw: (N,768) bf16 row-major. 128x128 tile, BK=32,
// 4 waves (2x2), 16x16x32 MFMA. LDS slot-XOR swizzle keeps ds_read_b128 2-way-free.
// MODE 0: scatter-store bf16 into Q/K/V (B,nh,S,hd).  MODE 1: fp32 store to out.
template<int N, int MODE>
__global__ __launch_bounds__(256, 2)
void gemm_nt(const unsigned short* __restrict__ A,
             const unsigned short* __restrict__ Bw,
             const float* __restrict__ bias,
             unsigned short* __restrict__ qkv_base,
             float* __restrict__ outp)
{
  __shared__ unsigned short As[128*32];
  __shared__ unsigned short Bs[128*32];
  const int tid  = threadIdx.x;
  const int lane = tid & 63;
  const int wid  = tid >> 6;
  const int g = lane >> 4, lr = lane & 15;
  const int wm = wid >> 1, wn = wid & 1;
  const int n0 = blockIdx.x * 128;
  const int m0 = blockIdx.y * 128;

  f32x4 acc[4][4];
  #pragma unroll
  for (int i = 0; i < 4; ++i)
    #pragma unroll
    for (int j = 0; j < 4; ++j) acc[i][j] = f32x4{0.f, 0.f, 0.f, 0.f};

  for (int k0 = 0; k0 < K_; k0 += 32) {
    #pragma unroll
    for (int it = 0; it < 2; ++it) {
      int chunk = tid + it * 256;          // 512 chunks of 8 bf16
      int row = chunk >> 2, slot = chunk & 3;
      int sw = (slot ^ ((row >> 1) & 3)) * 8;
      *reinterpret_cast<uint4*>(&As[row*32 + sw]) =
          *reinterpret_cast<const uint4*>(&A[(size_t)(m0 + row) * K_ + k0 + slot*8]);
      *reinterpret_cast<uint4*>(&Bs[row*32 + sw]) =
          *reinterpret_cast<const uint4*>(&Bw[(size_t)(n0 + row) * K_ + k0 + slot*8]);
    }
    __syncthreads();
    bf16x8 af[4], bfr[4];
    #pragma unroll
    for (int i = 0; i < 4; ++i) {
      int ra = wm*64 + i*16 + lr;
      af[i]  = *reinterpret_cast<const bf16x8*>(&As[ra*32 + ((g ^ ((ra>>1)&3))*8)]);
      int rb = wn*64 + i*16 + lr;
      bfr[i] = *reinterpret_cast<const bf16x8*>(&Bs[rb*32 + ((g ^ ((rb>>1)&3))*8)]);
    }
    #pragma unroll
    for (int i = 0; i < 4; ++i)
      #pragma unroll
      for (int j = 0; j < 4; ++j)
        acc[i][j] = __builtin_amdgcn_mfma_f32_16x16x32_bf16(af[i], bfr[j], acc[i][j], 0, 0, 0);
    __syncthreads();
  }

  // epilogue: C row = m0+wm*64+i*16+g*4+r, col = n0+wn*64+j*16+lr  (m89 layout)
  #pragma unroll
  for (int j = 0; j < 4; ++j) {
    int col = n0 + wn*64 + j*16 + lr;
    float bv = bias[col];
    if constexpr (MODE == 0) {
      int which = col / 768;               // 0=Q 1=K 2=V (frag never crosses boundary)
      int rem = col - which * 768;
      int h = rem >> 6, d = rem & 63;
      unsigned short* dst = qkv_base + (size_t)which * QKV_ELEMS;
      #pragma unroll
      for (int i = 0; i < 4; ++i)
        #pragma unroll
        for (int r = 0; r < 4; ++r) {
          int rowm = m0 + wm*64 + i*16 + g*4 + r;
          int bb = rowm >> 11, ss = rowm & 2047;
          dst[(((size_t)(bb*NH_ + h))*S_ + ss)*HD_ + d] = f2bf(acc[i][j][r] + bv);
        }
    } else {
      #pragma unroll
      for (int i = 0; i < 4; ++i)
        #pragma unroll
        for (int r = 0; r < 4; ++r) {
          int rowm = m0 + wm*64 + i*16 + g*4 + r;
          outp[(size_t)rowm * H_ + col] = acc[i][j][r] + bv;
        }
    }
  }
}

// ---------------- flash attention (causal), per (b,h,q-tile of 64) ----------------
// 4 waves x 16 q-rows. KV tiles of 64. K staged swizzled in LDS; V staged
// transposed+swizzled so PV B-frags are b128; P re-laid-out via per-wave LDS.
__global__ __launch_bounds__(256, 2)
void attn_fwd(const unsigned short* __restrict__ Qp,
              const unsigned short* __restrict__ Kp,
              const unsigned short* __restrict__ Vp,
              unsigned short* __restrict__ attn)
{
  __shared__ unsigned short Kl[64*64];     // [kv][d], slot = (d/8)^(kv&7)
  __shared__ unsigned short Vt[64*64];     // [d][kv], slot = (kv/8)^(d&7)
  __shared__ unsigned short Pl[4][16*72];  // per-wave P[16q][64kv], pad->72
  const int tid = threadIdx.x;
  const int lane = tid & 63, w = tid >> 6;
  const int g = lane >> 4, lr = lane & 15;
  const int qt = (int)gridDim.x - 1 - (int)blockIdx.x;  // heavy tiles first
  const int bh = blockIdx.y;                             // b*NH_+h
  const unsigned short* Qh = Qp + (size_t)bh * S_ * HD_;
  const unsigned short* Kh = Kp + (size_t)bh * S_ * HD_;
  const unsigned short* Vh = Vp + (size_t)bh * S_ * HD_;
  const int qbase = qt*64 + w*16;
  const int srow = tid >> 2, sseg = tid & 3;   // staging: row 0..63, 16-elem seg

  bf16x8 qf[2];
  #pragma unroll
  for (int ks = 0; ks < 2; ++ks)
    qf[ks] = *reinterpret_cast<const bf16x8*>(&Qh[(size_t)(qbase + lr)*HD_ + ks*32 + g*8]);

  f32x4 oacc[4];
  #pragma unroll
  for (int nn = 0; nn < 4; ++nn) oacc[nn] = f32x4{0.f,0.f,0.f,0.f};
  float mrun[4], lrun[4];
  #pragma unroll
  for (int r = 0; r < 4; ++r) { mrun[r] = -__builtin_inff(); lrun[r] = 0.f; }

  const int nt = qt + 1;
  for (int t = 0; t < nt; ++t) {
    const int kv0 = t * 64;
    // ---- stage K tile (vector, swizzled) ----
    #pragma unroll
    for (int c = 0; c < 2; ++c) {
      int slot = sseg*2 + c;
      *reinterpret_cast<uint4*>(&Kl[srow*64 + ((slot ^ (srow & 7)) * 8)]) =
          *reinterpret_cast<const uint4*>(&Kh[(size_t)(kv0 + srow)*HD_ + slot*8]);
    }
    // ---- stage V tile transposed (scalar writes, swizzled) ----
    #pragma unroll
    for (int c = 0; c < 2; ++c) {
      uint4 vd = *reinterpret_cast<const uint4*>(&Vh[(size_t)(kv0 + srow)*HD_ + sseg*16 + c*8]);
      unsigned int wv[4] = {vd.x, vd.y, vd.z, vd.w};
      #pragma unroll
      for (int e = 0; e < 4; ++e) {
        int d0 = sseg*16 + c*8 + e*2;
        Vt[ d0   *64 + (((srow>>3) ^ ( d0   &7))*8) + (srow&7)] = (unsigned short)(wv[e] & 0xFFFFu);
        Vt[(d0+1)*64 + (((srow>>3) ^ ((d0+1)&7))*8) + (srow&7)] = (unsigned short)(wv[e] >> 16);
      }
    }
    __syncthreads();

    // ---- S = Q K^T (16q x 64kv per wave) ----
    f32x4 sf[4];
    #pragma unroll
    for (int n = 0; n < 4; ++n) {
      sf[n] = f32x4{0.f,0.f,0.f,0.f};
      #pragma unroll
      for (int ks = 0; ks < 2; ++ks) {
        int krow = n*16 + lr;
        bf16x8 kf = *reinterpret_cast<const bf16x8*>(&Kl[krow*64 + (((ks*4 + g) ^ (krow & 7))*8)]);
        sf[n] = __builtin_amdgcn_mfma_f32_16x16x32_bf16(qf[ks], kf, sf[n], 0, 0, 0);
      }
    }

    // ---- online softmax (per q-row r; row values live in 16-lane group) ----
    const bool diag = (t == qt);
    float pv[4][4];
    #pragma unroll
    for (int r = 0; r < 4; ++r) {
      int qrow = qbase + g*4 + r;
      float sv[4];
      #pragma unroll
      for (int n = 0; n < 4; ++n) {
        float x = sf[n][r] * 0.125f;           // 1/sqrt(64)
        if (diag) { int kv = kv0 + n*16 + lr; if (kv > qrow) x = -__builtin_inff(); }
        sv[n] = x;
      }
      float tmax = fmaxf(fmaxf(sv[0], sv[1]), fmaxf(sv[2], sv[3]));
      #pragma unroll
      for (int mk = 1; mk < 16; mk <<= 1) tmax = fmaxf(tmax, __shfl_xor(tmax, mk));
      float mnew = fmaxf(mrun[r], tmax);
      float corr = __expf(mrun[r] - mnew);
      float rs = 0.f;
      #pragma unroll
      for (int n = 0; n < 4; ++n) { float p = __expf(sv[n] - mnew); pv[n][r] = p; rs += p; }
      #pragma unroll
      for (int mk = 1; mk < 16; mk <<= 1) rs += __shfl_xor(rs, mk);
      lrun[r] = lrun[r] * corr + rs;
      mrun[r] = mnew;
      #pragma unroll
      for (int nn = 0; nn < 4; ++nn) oacc[nn][r] *= corr;
    }

    // ---- P: C-frag layout -> A-frag layout via per-wave LDS ----
    #pragma unroll
    for (int r = 0; r < 4; ++r)
      #pragma unroll
      for (int n = 0; n < 4; ++n)
        Pl[w][(g*4 + r)*72 + n*16 + lr] = f2bf(pv[n][r]);
    asm volatile("s_waitcnt lgkmcnt(0)" ::: "memory");   // cross-lane LDS visibility
    __builtin_amdgcn_sched_barrier(0);

    // ---- O += P V ----
    #pragma unroll
    for (int ks = 0; ks < 2; ++ks) {
      bf16x8 pa = *reinterpret_cast<const bf16x8*>(&Pl[w][lr*72 + ks*32 + g*8]);
      #pragma unroll
      for (int nn = 0; nn < 4; ++nn) {
        int drow = nn*16 + lr;
        bf16x8 vf = *reinterpret_cast<const bf16x8*>(&Vt[drow*64 + (((ks*4 + g) ^ (drow & 7))*8)]);
        oacc[nn] = __builtin_amdgcn_mfma_f32_16x16x32_bf16(pa, vf, oacc[nn], 0, 0, 0);
      }
    }
    __syncthreads();
  }

  // ---- normalize + store (B,S,H) bf16 ----
  const int bb = bh / NH_, hh = bh % NH_;
  #pragma unroll
  for (int r = 0; r < 4; ++r) {
    float inv = 1.0f / lrun[r];
    int q = qbase + g*4 + r;
    size_t base = ((size_t)(bb*S_ + q))*H_ + hh*HD_;
    #pragma unroll
    for (int nn = 0; nn < 4; ++nn)
      attn[base + nn*16 + lr] = f2bf(oacc[nn][r] * inv);
  }
}

// ---------------- launch ----------------
extern "C" void kernel_launch(void* const* d_in, const int* in_sizes, int n_in,
                              void* d_out, int out_size, void* d_ws, size_t ws_size,
                              hipStream_t stream)
{
  const float* x      = (const float*)d_in[0];
  const float* w_qkv  = (const float*)d_in[1];
  const float* b_qkv  = (const float*)d_in[2];
  const float* w_o    = (const float*)d_in[3];
  const float* b_o    = (const float*)d_in[4];
  float* out = (float*)d_out;

  unsigned short* xb    = (unsigned short*)d_ws;          // 4096x768
  unsigned short* wqkvb = xb    + (size_t)M_ * K_;        // 2304x768
  unsigned short* wob   = wqkvb + (size_t)N_QKV * K_;     // 768x768
  unsigned short* Qw    = wob   + (size_t)H_ * H_;        // (B,nh,S,hd)
  unsigned short* Kw    = Qw + (size_t)QKV_ELEMS;
  unsigned short* Vw    = Kw + (size_t)QKV_ELEMS;
  unsigned short* attn  = Vw + (size_t)QKV_ELEMS;         // 4096x768

  cast3<<<5376, 256, 0, stream>>>(x, xb, 786432,
                                  w_qkv, wqkvb, 442368,
                                  w_o, wob, 147456);
  gemm_nt<N_QKV, 0><<<dim3(18, 32), 256, 0, stream>>>(xb, wqkvb, b_qkv, Qw, nullptr);
  attn_fwd<<<dim3(32, B_*NH_), 256, 0, stream>>>(Qw, Kw, Vw, attn);
  gemm_nt<H_, 1><<<dim3(6, 32), 256, 0, stream>>>(attn, wob, b_o, nullptr, out);
}

// Round 2
// 136.470 us; speedup vs baseline: 1.1658x; 1.1658x over previous
//
#include <hip/hip_runtime.h>
#include <stdint.h>

// GPT2 attention fused pipeline, MI355X/gfx950.
// B=2, S=2048, H=768, nh=12, hd=64. fp32 I/O, bf16 internal compute (MFMA).

#define B_   2
#define S_   2048
#define H_   768
#define NH_  12
#define HD_  64
#define M_   4096      // B_*S_
#define K_   768
#define N_QKV 2304
#define QKV_ELEMS (B_*NH_*S_*HD_)   // 3145728 per tensor (Q or K or V)
#define INF_ __builtin_inff()

using bf16x8 = __attribute__((ext_vector_type(8))) __bf16;
using f32x4  = __attribute__((ext_vector_type(4))) float;
using f32x16 = __attribute__((ext_vector_type(16))) float;

__device__ inline unsigned short f2bf(float f) {
  unsigned int u = __float_as_uint(f);
  u = (u + 0x7FFFu + ((u >> 16) & 1u)) >> 16;   // RNE
  return (unsigned short)u;
}

// ---------------- cast fp32 -> bf16 (3 tensors in one launch) ----------------
__global__ void cast3(const float* __restrict__ s0, unsigned short* __restrict__ d0, int n0f,
                      const float* __restrict__ s1, unsigned short* __restrict__ d1, int n1f,
                      const float* __restrict__ s2, unsigned short* __restrict__ d2, int n2f) {
  int i = blockIdx.x * blockDim.x + threadIdx.x;
  const float* s; unsigned short* d; int j;
  if (i < n0f)                { s = s0; d = d0; j = i; }
  else if (i < n0f + n1f)     { s = s1; d = d1; j = i - n0f; }
  else if (i < n0f + n1f + n2f) { s = s2; d = d2; j = i - n0f - n1f; }
  else return;
  float4 v = reinterpret_cast<const float4*>(s)[j];
  ushort4 o;
  o.x = f2bf(v.x); o.y = f2bf(v.y); o.z = f2bf(v.z); o.w = f2bf(v.w);
  reinterpret_cast<ushort4*>(d)[j] = o;
}

// ---------------- NT GEMM: C[m,n] = sum_k A[m,k]*Bw[n,k] + bias[n] ----------------
template<int N, int MODE>
__global__ __launch_bounds__(256, 2)
void gemm_nt(const unsigned short* __restrict__ A,
             const unsigned short* __restrict__ Bw,
             const float* __restrict__ bias,
             unsigned short* __restrict__ qkv_base,
             float* __restrict__ outp)
{
  __shared__ unsigned short As[128*32];
  __shared__ unsigned short Bs[128*32];
  const int tid  = threadIdx.x;
  const int lane = tid & 63;
  const int wid  = tid >> 6;
  const int g = lane >> 4, lr = lane & 15;
  const int wm = wid >> 1, wn = wid & 1;
  const int n0 = blockIdx.x * 128;
  const int m0 = blockIdx.y * 128;

  f32x4 acc[4][4];
  #pragma unroll
  for (int i = 0; i < 4; ++i)
    #pragma unroll
    for (int j = 0; j < 4; ++j) acc[i][j] = f32x4{0.f, 0.f, 0.f, 0.f};

  for (int k0 = 0; k0 < K_; k0 += 32) {
    #pragma unroll
    for (int it = 0; it < 2; ++it) {
      int chunk = tid + it * 256;          // 512 chunks of 8 bf16
      int row = chunk >> 2, slot = chunk & 3;
      int sw = (slot ^ ((row >> 1) & 3)) * 8;
      *reinterpret_cast<uint4*>(&As[row*32 + sw]) =
          *reinterpret_cast<const uint4*>(&A[(size_t)(m0 + row) * K_ + k0 + slot*8]);
      *reinterpret_cast<uint4*>(&Bs[row*32 + sw]) =
          *reinterpret_cast<const uint4*>(&Bw[(size_t)(n0 + row) * K_ + k0 + slot*8]);
    }
    __syncthreads();
    bf16x8 af[4], bfr[4];
    #pragma unroll
    for (int i = 0; i < 4; ++i) {
      int ra = wm*64 + i*16 + lr;
      af[i]  = *reinterpret_cast<const bf16x8*>(&As[ra*32 + ((g ^ ((ra>>1)&3))*8)]);
      int rb = wn*64 + i*16 + lr;
      bfr[i] = *reinterpret_cast<const bf16x8*>(&Bs[rb*32 + ((g ^ ((rb>>1)&3))*8)]);
    }
    #pragma unroll
    for (int i = 0; i < 4; ++i)
      #pragma unroll
      for (int j = 0; j < 4; ++j)
        acc[i][j] = __builtin_amdgcn_mfma_f32_16x16x32_bf16(af[i], bfr[j], acc[i][j], 0, 0, 0);
    __syncthreads();
  }

  #pragma unroll
  for (int j = 0; j < 4; ++j) {
    int col = n0 + wn*64 + j*16 + lr;
    float bv = bias[col];
    if constexpr (MODE == 0) {
      int which = col / 768;               // 0=Q 1=K 2=V
      int rem = col - which * 768;
      int h = rem >> 6, d = rem & 63;
      unsigned short* dst = qkv_base + (size_t)which * QKV_ELEMS;
      #pragma unroll
      for (int i = 0; i < 4; ++i)
        #pragma unroll
        for (int r = 0; r < 4; ++r) {
          int rowm = m0 + wm*64 + i*16 + g*4 + r;
          int bb = rowm >> 11, ss = rowm & 2047;
          dst[(((size_t)(bb*NH_ + h))*S_ + ss)*HD_ + d] = f2bf(acc[i][j][r] + bv);
        }
    } else {
      #pragma unroll
      for (int i = 0; i < 4; ++i)
        #pragma unroll
        for (int r = 0; r < 4; ++r) {
          int rowm = m0 + wm*64 + i*16 + g*4 + r;
          outp[(size_t)rowm * H_ + col] = acc[i][j][r] + bv;
        }
    }
  }
}

// ---------------- flash attention (causal), 32x32x16 MFMA, swapped operands --------
// Block = 2 waves, q-tile = 32 rows (shared by both waves), KV tile = 64 split
// 32/32 across the waves (partial m/l/O merged once per q-tile).
// Each block processes the paired q-tiles (blockIdx.x, 63-blockIdx.x) -> uniform work.
// S^T = K·Q^T so softmax is lane-local; O^T = V^T·P^T so rescale is lane-local.
// K/V double-buffered in LDS; prefetch loads issued before compute, written after.
__global__ __launch_bounds__(128, 4)
void attn_fwd(const unsigned short* __restrict__ Qp,
              const unsigned short* __restrict__ Kp,
              const unsigned short* __restrict__ Vp,
              unsigned short* __restrict__ attn)
{
  __shared__ __align__(16) char smem[37888];
  unsigned short* Kl = (unsigned short*)smem;            // [2][64*64] swizzled
  unsigned short* Vt = (unsigned short*)(smem + 16384);  // [2][64*64] transposed+swizzled
  unsigned short* Pl = (unsigned short*)(smem + 32768);  // [2 waves][32*40]
  float*  Osc = (float*)smem;                            // [2][32][68] (overlay, merge phase)
  float*  mlb = (float*)(smem + 32768);                  // [2 waves][{m[32], l[32]}]

  const int tid = threadIdx.x;
  const int l   = tid & 63, w = tid >> 6;
  const int q31 = l & 31, hi = l >> 5;
  const int bh  = blockIdx.y;
  const unsigned short* Qh = Qp + (size_t)bh * S_ * HD_;
  const unsigned short* Kh = Kp + (size_t)bh * S_ * HD_;
  const unsigned short* Vh = Vp + (size_t)bh * S_ * HD_;
  const int bb = bh / NH_, hh = bh % NH_;

  for (int qi = 0; qi < 2; ++qi) {
    const int qt = qi ? (63 - (int)blockIdx.x) : (int)blockIdx.x;
    const int qb = qt * 32;
    const int nt = (qt >> 1) + 1;
    const int qrow = qb + q31;

    // Q fragments (B-operand: col = q31, k-chunks over d)
    bf16x8 qf[4];
    #pragma unroll
    for (int ks = 0; ks < 4; ++ks)
      qf[ks] = *reinterpret_cast<const bf16x8*>(&Qh[(size_t)qrow * HD_ + ks*16 + hi*8]);

    f32x16 oacc[2];
    #pragma unroll
    for (int m2 = 0; m2 < 2; ++m2)
      #pragma unroll
      for (int r = 0; r < 16; ++r) oacc[m2][r] = 0.f;
    float mrun = -INF_, lrun = 0.f;

    // ---- staging helpers (K: 4 b128 chunks; V: 2 units of paired rows) ----
    uint4 kg[4], va[2], vb[2];
    auto ldKV = [&](int tile) {
      #pragma unroll
      for (int it = 0; it < 4; ++it) {
        int c = tid + it*128; int row = c >> 3, seg = c & 7;
        kg[it] = *reinterpret_cast<const uint4*>(&Kh[(size_t)(tile*64 + row)*HD_ + seg*8]);
      }
      #pragma unroll
      for (int it = 0; it < 2; ++it) {
        int u = tid + it*128; int p = u >> 3, s = u & 7;
        va[it] = *reinterpret_cast<const uint4*>(&Vh[(size_t)(tile*64 + 2*p    )*HD_ + s*8]);
        vb[it] = *reinterpret_cast<const uint4*>(&Vh[(size_t)(tile*64 + 2*p + 1)*HD_ + s*8]);
      }
    };
    auto stKV = [&](int buf) {
      unsigned short* Kb = Kl + buf*4096;
      char* Vb = (char*)(Vt + buf*4096);
      #pragma unroll
      for (int it = 0; it < 4; ++it) {
        int c = tid + it*128; int row = c >> 3, seg = c & 7;
        *reinterpret_cast<uint4*>(&Kb[row*64 + ((seg ^ (row & 7)) * 8)]) = kg[it];
      }
      #pragma unroll
      for (int it = 0; it < 2; ++it) {
        int u = tid + it*128; int p = u >> 3, s = u & 7;
        unsigned aw[4] = {va[it].x, va[it].y, va[it].z, va[it].w};
        unsigned bw[4] = {vb[it].x, vb[it].y, vb[it].z, vb[it].w};
        #pragma unroll
        for (int e = 0; e < 8; ++e) {
          int d = s*8 + e;
          unsigned lo  = (e & 1) ? (aw[e>>1] >> 16)        : (aw[e>>1] & 0xFFFFu);
          unsigned hw  = (e & 1) ? (bw[e>>1] & 0xFFFF0000u) : (bw[e>>1] << 16);
          *reinterpret_cast<unsigned*>(Vb + d*128 + (((p>>2) ^ s) & 7)*16 + (p & 3)*4) = lo | hw;
        }
      }
    };

    ldKV(0); stKV(0);
    __syncthreads();
    int cur = 0;

    for (int t = 0; t < nt; ++t) {
      const bool pf = (t + 1 < nt);
      if (pf) ldKV(t + 1);               // issue early; latency hides under compute

      // ---- S^T = K · Q^T (wave's 32 kv rows x 32 q cols) ----
      f32x16 sf;
      #pragma unroll
      for (int r = 0; r < 16; ++r) sf[r] = 0.f;
      const int krow = w*32 + q31;
      #pragma unroll
      for (int ks = 0; ks < 4; ++ks) {
        int chunk = ks*2 + hi;
        bf16x8 kf = *reinterpret_cast<const bf16x8*>(
            &Kl[cur*4096 + krow*64 + (((chunk ^ (krow & 7)) & 7) * 8)]);
        sf = __builtin_amdgcn_mfma_f32_32x32x16_bf16(kf, qf[ks], sf, 0, 0, 0);
      }

      // ---- lane-local online softmax (lane owns q-row q31's 16 scores) ----
      const bool last = (t == nt - 1);
      float sv[16];
      float mt = -INF_;
      #pragma unroll
      for (int r = 0; r < 16; ++r) {
        float x = sf[r] * 0.125f;                  // 1/sqrt(64)
        if (last) {
          int crow = (r & 3) + 8*(r >> 2) + 4*hi;
          int kv = t*64 + w*32 + crow;
          if (kv > qrow) x = -INF_;
        }
        sv[r] = x; mt = fmaxf(mt, x);
      }
      mt = fmaxf(mt, __shfl_xor(mt, 32));
      float mnew = fmaxf(mrun, mt);
      bool dead = (mnew == -INF_);                 // wave half entirely masked so far
      float corr = dead ? 1.f : __expf(mrun - mnew);
      float rs = 0.f;
      unsigned pw[8];
      #pragma unroll
      for (int r = 0; r < 16; r += 2) {
        float p0 = dead ? 0.f : __expf(sv[r]   - mnew);
        float p1 = dead ? 0.f : __expf(sv[r+1] - mnew);
        rs += p0 + p1;
        pw[r >> 1] = (unsigned)f2bf(p0) | ((unsigned)f2bf(p1) << 16);
      }
      rs += __shfl_xor(rs, 32);
      lrun = lrun * corr + rs;
      mrun = mnew;
      #pragma unroll
      for (int m2 = 0; m2 < 2; ++m2)
        #pragma unroll
        for (int r = 0; r < 16; ++r) oacc[m2][r] *= corr;

      // ---- P (bf16) -> per-wave LDS [q][kv_local], row stride 40 ----
      #pragma unroll
      for (int rr = 0; rr < 4; ++rr) {
        uint2 u2; u2.x = pw[2*rr]; u2.y = pw[2*rr + 1];
        *reinterpret_cast<uint2*>(&Pl[w*1280 + q31*40 + rr*8 + 4*hi]) = u2;
      }
      asm volatile("s_waitcnt lgkmcnt(0)" ::: "memory");
      __builtin_amdgcn_sched_barrier(0);

      // ---- O^T += V^T · P^T ----
      #pragma unroll
      for (int ks2 = 0; ks2 < 2; ++ks2) {
        bf16x8 pa = *reinterpret_cast<const bf16x8*>(&Pl[w*1280 + q31*40 + ks2*16 + hi*8]);
        #pragma unroll
        for (int m2 = 0; m2 < 2; ++m2) {
          int d = m2*32 + q31;
          int chunk = 4*w + 2*ks2 + hi;
          bf16x8 vf = *reinterpret_cast<const bf16x8*>(
              &Vt[cur*4096 + d*64 + (((chunk ^ (d >> 3)) & 7) * 8)]);
          oacc[m2] = __builtin_amdgcn_mfma_f32_32x32x16_bf16(vf, pa, oacc[m2], 0, 0, 0);
        }
      }

      if (pf) stKV(cur ^ 1);             // write prefetched tile (vmcnt waits auto)
      __syncthreads();
      cur ^= 1;
    }

    // ---- write partial O^T (f32) + m/l; merge the two waves; store ----
    #pragma unroll
    for (int m2 = 0; m2 < 2; ++m2)
      #pragma unroll
      for (int rr = 0; rr < 4; ++rr) {
        f32x4 v4;
        v4[0] = oacc[m2][4*rr]; v4[1] = oacc[m2][4*rr+1];
        v4[2] = oacc[m2][4*rr+2]; v4[3] = oacc[m2][4*rr+3];
        int dbase = m2*32 + 8*rr + 4*hi;
        *reinterpret_cast<f32x4*>(&Osc[(w*32 + q31)*68 + dbase]) = v4;
      }
    if (l < 32) { mlb[w*64 + q31] = mrun; mlb[w*64 + 32 + q31] = lrun; }
    __syncthreads();

    #pragma unroll
    for (int it = 0; it < 2; ++it) {
      int u = tid + it*128;
      int q = u >> 3, ch = u & 7;
      float m0 = mlb[q],      l0 = mlb[32 + q];
      float m1 = mlb[64 + q], l1 = mlb[96 + q];
      float M  = fmaxf(m0, m1);
      float e0 = (m0 == -INF_) ? 0.f : __expf(m0 - M);
      float e1 = (m1 == -INF_) ? 0.f : __expf(m1 - M);
      float inv = 1.f / (l0*e0 + l1*e1);
      f32x4 a0 = *reinterpret_cast<f32x4*>(&Osc[q*68 + ch*8]);
      f32x4 a1 = *reinterpret_cast<f32x4*>(&Osc[q*68 + ch*8 + 4]);
      f32x4 b0 = *reinterpret_cast<f32x4*>(&Osc[(32 + q)*68 + ch*8]);
      f32x4 b1 = *reinterpret_cast<f32x4*>(&Osc[(32 + q)*68 + ch*8 + 4]);
      unsigned ow[4];
      #pragma unroll
      for (int j = 0; j < 4; ++j) {
        unsigned short e = f2bf((a0[j]*e0 + b0[j]*e1) * inv);
        unsigned short o = f2bf((a1[j]*e0 + b1[j]*e1) * inv);
        if (j < 2) { ow[j]   = 0; }
        (void)e; (void)o;
      }
      // build 8 bf16 words explicitly
      unsigned w0 = (unsigned)f2bf((a0[0]*e0 + b0[0]*e1) * inv) |
                    ((unsigned)f2bf((a0[1]*e0 + b0[1]*e1) * inv) << 16);
      unsigned w1 = (unsigned)f2bf((a0[2]*e0 + b0[2]*e1) * inv) |
                    ((unsigned)f2bf((a0[3]*e0 + b0[3]*e1) * inv) << 16);
      unsigned w2 = (unsigned)f2bf((a1[0]*e0 + b1[0]*e1) * inv) |
                    ((unsigned)f2bf((a1[1]*e0 + b1[1]*e1) * inv) << 16);
      unsigned w3 = (unsigned)f2bf((a1[2]*e0 + b1[2]*e1) * inv) |
                    ((unsigned)f2bf((a1[3]*e0 + b1[3]*e1) * inv) << 16);
      uint4 ov; ov.x = w0; ov.y = w1; ov.z = w2; ov.w = w3;
      *reinterpret_cast<uint4*>(&attn[((size_t)(bb*S_ + qb + q))*H_ + hh*HD_ + ch*8]) = ov;
    }
    __syncthreads();   // Osc overlays Kl/Vt: drain before next q-tile restages
  }
}

// ---------------- launch ----------------
extern "C" void kernel_launch(void* const* d_in, const int* in_sizes, int n_in,
                              void* d_out, int out_size, void* d_ws, size_t ws_size,
                              hipStream_t stream)
{
  const float* x      = (const float*)d_in[0];
  const float* w_qkv  = (const float*)d_in[1];
  const float* b_qkv  = (const float*)d_in[2];
  const float* w_o    = (const float*)d_in[3];
  const float* b_o    = (const float*)d_in[4];
  float* out = (float*)d_out;

  unsigned short* xb    = (unsigned short*)d_ws;          // 4096x768
  unsigned short* wqkvb = xb    + (size_t)M_ * K_;        // 2304x768
  unsigned short* wob   = wqkvb + (size_t)N_QKV * K_;     // 768x768
  unsigned short* Qw    = wob   + (size_t)H_ * H_;        // (B,nh,S,hd)
  unsigned short* Kw    = Qw + (size_t)QKV_ELEMS;
  unsigned short* Vw    = Kw + (size_t)QKV_ELEMS;
  unsigned short* attn  = Vw + (size_t)QKV_ELEMS;         // 4096x768

  cast3<<<5376, 256, 0, stream>>>(x, xb, 786432,
                                  w_qkv, wqkvb, 442368,
                                  w_o, wob, 147456);
  gemm_nt<N_QKV, 0><<<dim3(18, 32), 256, 0, stream>>>(xb, wqkvb, b_qkv, Qw, nullptr);
  attn_fwd<<<dim3(32, B_*NH_), 128, 0, stream>>>(Qw, Kw, Vw, attn);
  gemm_nt<H_, 1><<<dim3(6, 32), 256, 0, stream>>>(attn, wob, b_o, nullptr, out);
}